// Round 1
// baseline (5802.594 us; speedup 1.0000x reference)
//
#include <hip/hip_runtime.h>
#include <hip/hip_bf16.h>
#include <math.h>

#define HDIM 1024
#define BROWS 16384
#define TSTEPS 8
#define NCOLS 8192   // 1024 op1 | 1024 num1 | 3072 gi | 3072 gh

typedef __bf16 bf16;
typedef __attribute__((ext_vector_type(8))) __bf16 bf16x8;
typedef __attribute__((ext_vector_type(4))) __bf16 bf16x4;
typedef __attribute__((ext_vector_type(4))) float f32x4;

__device__ __forceinline__ void async_ld16(void* lds, const void* g) {
  __builtin_amdgcn_global_load_lds((__attribute__((address_space(1))) void*)g,
                                   (__attribute__((address_space(3))) void*)lds,
                                   16, 0, 0);
}

__device__ __forceinline__ float gelu_exact(float x) {
  return 0.5f * x * (1.0f + erff(x * 0.70710678118654752f));
}
__device__ __forceinline__ float sigmoidf_(float x) {
  return 1.0f / (1.0f + __expf(-x));
}

// ---------------- weight prep ----------------
// Wcat[n][k] (bf16, row-major, n in [0,8192), k in [0,1024)):
//   n in [0,1024):    w_op1[k][n]   (transpose)
//   n in [1024,2048): w_num1[k][n-1024]
//   n in [2048,5120): w_ih[n-2048][k]  (direct copy)
//   n in [5120,8192): w_hh[n-5120][k]
__global__ void prep_trans(const float* __restrict__ w_op1, const float* __restrict__ w_num1,
                           bf16* __restrict__ Wcat) {
  __shared__ float tile[32][33];
  const float* src = blockIdx.z ? w_num1 : w_op1;
  const int cofs = blockIdx.z * 1024;
  const int kt = blockIdx.y * 32, nt = blockIdx.x * 32;
  const int tx = threadIdx.x, ty = threadIdx.y;  // 32 x 8
#pragma unroll
  for (int r = 0; r < 4; ++r) {
    int k = kt + ty + r * 8;
    tile[ty + r * 8][tx] = src[(size_t)k * HDIM + nt + tx];
  }
  __syncthreads();
#pragma unroll
  for (int r = 0; r < 4; ++r) {
    int n = nt + ty + r * 8;
    Wcat[(size_t)(cofs + n) * HDIM + kt + tx] = (bf16)tile[tx][ty + r * 8];
  }
}

__global__ void prep_gate(const float* __restrict__ w_ih, const float* __restrict__ w_hh,
                          bf16* __restrict__ Wcat) {
  size_t i = (size_t)blockIdx.x * 256 + threadIdx.x;  // over 2 * 3072*1024/4
  const size_t half = (size_t)3 * HDIM * HDIM / 4;    // 786432 float4s
  const float* src = (i < half) ? w_ih : w_hh;
  size_t ofs = (i < half) ? i : i - half;
  size_t dofs = (i < half) ? (size_t)2048 * HDIM / 4 : (size_t)5120 * HDIM / 4;
  float4 v = ((const float4*)src)[ofs];
  bf16x4 b = {(bf16)v.x, (bf16)v.y, (bf16)v.z, (bf16)v.w};
  ((bf16x4*)Wcat)[dofs + ofs] = b;
}

__global__ void prep_bias(const float* __restrict__ b_op1, const float* __restrict__ b_num1,
                          const float* __restrict__ b_ih, const float* __restrict__ b_hh,
                          float* __restrict__ bias) {
  int n = blockIdx.x * 256 + threadIdx.x;
  float v;
  if (n < 1024) v = b_op1[n];
  else if (n < 2048) v = b_num1[n - 1024];
  else if (n < 5120) v = b_ih[n - 2048];
  else v = b_hh[n - 5120];
  bias[n] = v;
}

__global__ void convert_x(const float* __restrict__ x, float* __restrict__ st0,
                          bf16* __restrict__ hbf) {
  size_t i = (size_t)blockIdx.x * 256 + threadIdx.x;  // over B*H/4
  float4 v = ((const float4*)x)[i];
  ((float4*)st0)[i] = v;
  bf16x4 b = {(bf16)v.x, (bf16)v.y, (bf16)v.z, (bf16)v.w};
  ((bf16x4*)hbf)[i] = b;
}

// ---------------- main GEMM: C[chunk][8192] = A[chunk][1024] @ Wcat^T ----------------
// 128x128 tile, BK=64, 4 waves (2x2 of 64x64), 16x16x32 bf16 MFMA.
// LDS layout: 16B chunks (8 bf16) at physical index m*8 + (c ^ (m&7))  (XOR swizzle,
// so ds_read_b128 of MFMA fragments is 2-way bank aliased = free).
__global__ void __launch_bounds__(256) gemm_step(
    const bf16* __restrict__ A,      // chunk base, [rows][1024]
    const bf16* __restrict__ Bw,     // Wcat [8192][1024]
    const float* __restrict__ bias,  // [8192]
    bf16* __restrict__ C)            // [rows][8192]
{
  __shared__ __align__(16) bf16 At[128 * 64];
  __shared__ __align__(16) bf16 Bt[128 * 64];
  const int tid = threadIdx.x;
  const int wave = tid >> 6;
  const int lane = tid & 63;
  const int idx15 = lane & 15;
  const int quad = lane >> 4;
  const int tile_m = blockIdx.x * 128;
  const int tile_n = blockIdx.y * 128;
  const int wm = (wave >> 1) * 64;
  const int wn = (wave & 1) * 64;

  // staging: 16 instrs of 64 chunks; wave w issues q=0..3 for A and for B
  const bf16* ag[4];
  const bf16* bg[4];
  int lofs[4];
#pragma unroll
  for (int q = 0; q < 4; ++q) {
    int p = (wave * 4 + q) * 64 + lane;  // chunk id in [0,1024)
    int m = p >> 3;
    int c = (p & 7) ^ (m & 7);           // logical k-chunk for this physical slot
    ag[q] = A + (size_t)(tile_m + m) * HDIM + c * 8;
    bg[q] = Bw + (size_t)(tile_n + m) * HDIM + c * 8;
    lofs[q] = (wave * 4 + q) * 64 * 8;   // element offset of the 64-chunk block
  }

  f32x4 acc[4][4] = {};

  for (int kt = 0; kt < HDIM; kt += 64) {
    __syncthreads();
#pragma unroll
    for (int q = 0; q < 4; ++q) async_ld16(&At[lofs[q]], ag[q] + kt);
#pragma unroll
    for (int q = 0; q < 4; ++q) async_ld16(&Bt[lofs[q]], bg[q] + kt);
    asm volatile("s_waitcnt vmcnt(0)" ::: "memory");
    __syncthreads();
#pragma unroll
    for (int kk = 0; kk < 64; kk += 32) {
      const int c0 = (kk >> 3) + quad;  // logical k-chunk col for this quad
      bf16x8 af[4], bfr[4];
#pragma unroll
      for (int i = 0; i < 4; ++i) {
        int m = wm + i * 16 + idx15;
        af[i] = *(const bf16x8*)&At[(m * 8 + (c0 ^ (m & 7))) * 8];
      }
#pragma unroll
      for (int j = 0; j < 4; ++j) {
        int n = wn + j * 16 + idx15;
        bfr[j] = *(const bf16x8*)&Bt[(n * 8 + (c0 ^ (n & 7))) * 8];
      }
#pragma unroll
      for (int i = 0; i < 4; ++i)
#pragma unroll
        for (int j = 0; j < 4; ++j)
          acc[i][j] = __builtin_amdgcn_mfma_f32_16x16x32_bf16(af[i], bfr[j], acc[i][j], 0, 0, 0);
    }
  }

  const bool do_gelu = (tile_n < 2048);  // op/num head columns get exact GELU fused
#pragma unroll
  for (int j = 0; j < 4; ++j) {
    int n = tile_n + wn + j * 16 + idx15;
    float bv = bias[n];
#pragma unroll
    for (int i = 0; i < 4; ++i) {
      int m0 = tile_m + wm + i * 16 + quad * 4;
#pragma unroll
      for (int r = 0; r < 4; ++r) {
        float v = acc[i][j][r] + bv;
        if (do_gelu) v = gelu_exact(v);
        C[(size_t)(m0 + r) * NCOLS + n] = (bf16)v;
      }
    }
  }
}

// ---------------- per-step heads: ops[B,5], nums[B,1] ----------------
__global__ void __launch_bounds__(256) heads_step(
    const bf16* __restrict__ C, const float* __restrict__ w_op2,
    const float* __restrict__ b_op2, const float* __restrict__ w_num2,
    const float* __restrict__ b_num2, float* __restrict__ ops_t,
    float* __restrict__ nums_t, int row0) {
  const int wave = threadIdx.x >> 6;
  const int lane = threadIdx.x & 63;
  const int row = blockIdx.x * 4 + wave;
  const bf16* crow = C + (size_t)row * NCOLS;
  float a0 = 0, a1 = 0, a2 = 0, a3 = 0, a4 = 0, an = 0;
  for (int k = lane; k < HDIM; k += 64) {
    float hv = (float)crow[k];  // already GELU'd
    a0 += hv * w_op2[k * 5 + 0];
    a1 += hv * w_op2[k * 5 + 1];
    a2 += hv * w_op2[k * 5 + 2];
    a3 += hv * w_op2[k * 5 + 3];
    a4 += hv * w_op2[k * 5 + 4];
    an += (float)crow[HDIM + k] * w_num2[k];
  }
#pragma unroll
  for (int off = 32; off > 0; off >>= 1) {
    a0 += __shfl_down(a0, off);
    a1 += __shfl_down(a1, off);
    a2 += __shfl_down(a2, off);
    a3 += __shfl_down(a3, off);
    a4 += __shfl_down(a4, off);
    an += __shfl_down(an, off);
  }
  if (lane == 0) {
    size_t grow = (size_t)(row0 + row);
    ops_t[grow * 5 + 0] = a0 + b_op2[0];
    ops_t[grow * 5 + 1] = a1 + b_op2[1];
    ops_t[grow * 5 + 2] = a2 + b_op2[2];
    ops_t[grow * 5 + 3] = a3 + b_op2[3];
    ops_t[grow * 5 + 4] = a4 + b_op2[4];
    nums_t[grow] = an + b_num2[0];
  }
}

// ---------------- per-step GRU update ----------------
__global__ void __launch_bounds__(256) gru_step(
    const bf16* __restrict__ C, const float* __restrict__ h_old,
    float* __restrict__ h_new, bf16* __restrict__ hbf) {
  size_t i = (size_t)blockIdx.x * 256 + threadIdx.x;
  int row = (int)(i >> 10);
  int j = (int)(i & 1023);
  const bf16* crow = C + (size_t)row * NCOLS;
  float ir = (float)crow[2048 + j];
  float iz = (float)crow[3072 + j];
  float inn = (float)crow[4096 + j];
  float hr = (float)crow[5120 + j];
  float hz = (float)crow[6144 + j];
  float hn = (float)crow[7168 + j];
  float r = sigmoidf_(ir + hr);
  float z = sigmoidf_(iz + hz);
  float n = tanhf(inn + r * hn);
  float h = h_old[i];
  float v = (1.0f - z) * n + z * h;
  h_new[i] = v;
  hbf[i] = (bf16)v;
}

extern "C" void kernel_launch(void* const* d_in, const int* in_sizes, int n_in,
                              void* d_out, int out_size, void* d_ws, size_t ws_size,
                              hipStream_t stream) {
  const float* x      = (const float*)d_in[0];
  // d_in[1] = num_steps (always 8)
  const float* w_op1  = (const float*)d_in[2];
  const float* b_op1  = (const float*)d_in[3];
  const float* w_op2  = (const float*)d_in[4];
  const float* b_op2  = (const float*)d_in[5];
  const float* w_num1 = (const float*)d_in[6];
  const float* b_num1 = (const float*)d_in[7];
  const float* w_num2 = (const float*)d_in[8];
  const float* b_num2 = (const float*)d_in[9];
  const float* w_ih   = (const float*)d_in[10];
  const float* b_ih   = (const float*)d_in[11];
  const float* w_hh   = (const float*)d_in[12];
  const float* b_hh   = (const float*)d_in[13];

  float* out = (float*)d_out;
  float* final_state = out;                                  // [B,H]
  float* ops    = out + (size_t)BROWS * HDIM;                // [T,B,5]
  float* nums   = ops + (size_t)TSTEPS * BROWS * 5;          // [T,B,1]
  float* states = nums + (size_t)TSTEPS * BROWS;             // [T,B,H]

  char* ws = (char*)d_ws;
  bf16* Wcat  = (bf16*)ws;                                           // 16 MB
  float* bias = (float*)(ws + (size_t)NCOLS * HDIM * 2);             // 32 KB
  bf16* hbf   = (bf16*)(ws + (size_t)NCOLS * HDIM * 2 + NCOLS * 4);  // 32 MB
  char* cbase = ws + (size_t)NCOLS * HDIM * 2 + NCOLS * 4 + (size_t)BROWS * HDIM * 2;
  bf16* C = (bf16*)cbase;
  size_t fixed = (size_t)(cbase - ws);

  // pick the largest chunk whose C buffer fits in the workspace
  int nch = 1;
  while (nch < 64 && fixed + (size_t)(BROWS / nch) * NCOLS * 2 > ws_size) nch *= 2;
  const int chunk = BROWS / nch;

  prep_trans<<<dim3(32, 32, 2), dim3(32, 8), 0, stream>>>(w_op1, w_num1, Wcat);
  prep_gate<<<6144, 256, 0, stream>>>(w_ih, w_hh, Wcat);
  prep_bias<<<NCOLS / 256, 256, 0, stream>>>(b_op1, b_num1, b_ih, b_hh, bias);
  convert_x<<<(BROWS * HDIM / 4) / 256, 256, 0, stream>>>(x, states, hbf);

  for (int t = 0; t < TSTEPS; ++t) {
    float* st    = states + (size_t)t * BROWS * HDIM;
    float* stn   = (t == TSTEPS - 1) ? final_state : states + (size_t)(t + 1) * BROWS * HDIM;
    float* ops_t = ops + (size_t)t * BROWS * 5;
    float* nums_t = nums + (size_t)t * BROWS;
    for (int c = 0; c < nch; ++c) {
      size_t r0 = (size_t)c * chunk;
      gemm_step<<<dim3(chunk / 128, NCOLS / 128), 256, 0, stream>>>(
          hbf + r0 * HDIM, Wcat, bias, C);
      heads_step<<<chunk / 4, 256, 0, stream>>>(C, w_op2, b_op2, w_num2, b_num2,
                                                ops_t, nums_t, (int)r0);
      gru_step<<<(chunk * HDIM) / 256, 256, 0, stream>>>(C, st + r0 * HDIM,
                                                         stn + r0 * HDIM, hbf + r0 * HDIM);
    }
  }
}